// Round 2
// baseline (996.462 us; speedup 1.0000x reference)
//
#include <hip/hip_runtime.h>

// ---- problem constants ----
#define H_     8
#define DM_    1024
#define NQKV_  4096
#define ROWS_  16384          // SLEN*BSZ = 256*64
#define PAIRS_ 512            // BSZ*H
#define SCALE_ 0.08838834764831845f
#define LN_EPS_ 1e-5f

typedef __attribute__((ext_vector_type(8))) short short8;   // 8 bf16 (4 VGPRs)
typedef __attribute__((ext_vector_type(4))) float floatx4;  // MFMA accumulator

__device__ __forceinline__ float b2f(unsigned short u) {
  union { unsigned int i; float f; } v; v.i = ((unsigned int)u) << 16; return v.f;
}
__device__ __forceinline__ unsigned short f2b(float f) {
  union { unsigned int i; float f; } v; v.f = f;
  unsigned int b = v.i;
  b += 0x7FFFu + ((b >> 16) & 1u);   // round-to-nearest-even
  return (unsigned short)(b >> 16);
}

// ---- stage 128x64 fp32 tile (row-major, ld elems) -> LDS bf16 [128][72] ----
__device__ __forceinline__ void stage_f32(const float* __restrict__ g, int ld,
                                          unsigned short* s, int tid) {
#pragma unroll
  for (int p = 0; p < 4; ++p) {
    int idx = p * 256 + tid;
    int r = idx >> 3, c = (idx & 7) << 3;
    const float* gp = g + (size_t)r * ld + c;
    float4 v0 = *(const float4*)gp;
    float4 v1 = *(const float4*)(gp + 4);
    union { short8 v; unsigned short u[8]; } pk;
    pk.u[0] = f2b(v0.x); pk.u[1] = f2b(v0.y); pk.u[2] = f2b(v0.z); pk.u[3] = f2b(v0.w);
    pk.u[4] = f2b(v1.x); pk.u[5] = f2b(v1.y); pk.u[6] = f2b(v1.z); pk.u[7] = f2b(v1.w);
    *(short8*)(s + r * 72 + c) = pk.v;
  }
}
// ---- stage 128x64 bf16 tile -> LDS [128][72] ----
__device__ __forceinline__ void stage_bf16(const unsigned short* __restrict__ g, int ld,
                                           unsigned short* s, int tid) {
#pragma unroll
  for (int p = 0; p < 4; ++p) {
    int idx = p * 256 + tid;
    int r = idx >> 3, c = (idx & 7) << 3;
    *(short8*)(s + r * 72 + c) = *(const short8*)(g + (size_t)r * ld + c);
  }
}

// =====================================================================
// K1: qkv gemm + scatter epilogue.
//   Y[row,n] = sum_m h[row,m]*Wqkv[n,m]; n-tile (128 cols) == one part of
//   one head, so epilogue scatters straight into pair-major buffers:
//   part<3 -> P[(pair*256+l)*128 + d]   (pre-phi values, bf16)
//   part=3 -> Vt[(pair*128+d)*256 + l]  (transposed, bf16)
// =====================================================================
__global__ __launch_bounds__(256) void qkv_gemm(const float* __restrict__ A,
                                                const float* __restrict__ B,
                                                unsigned short* __restrict__ QKV) {
  __shared__ alignas(16) unsigned short As[128 * 72], Bs[128 * 72];
  int tid = threadIdx.x;
  int lane = tid & 63, wid = tid >> 6;
  int wm = wid >> 1, wn = wid & 1;
  int quad = lane >> 4, l16 = lane & 15;
  int m0 = blockIdx.y * 128, n0 = blockIdx.x * 128;
  int hh = n0 >> 9, part = (n0 >> 7) & 3;
  const float* Ab = A + (size_t)m0 * DM_;
  const float* Bb = B + (size_t)n0 * DM_;

  floatx4 acc[4][4];
#pragma unroll
  for (int i = 0; i < 4; ++i)
#pragma unroll
    for (int j = 0; j < 4; ++j)
#pragma unroll
      for (int r = 0; r < 4; ++r) acc[i][j][r] = 0.f;

  for (int kt = 0; kt < DM_; kt += 64) {
    stage_f32(Ab + kt, DM_, As, tid);
    stage_f32(Bb + kt, DM_, Bs, tid);
    __syncthreads();
#pragma unroll
    for (int kk = 0; kk < 2; ++kk) {
      short8 af[4], bfv[4];
#pragma unroll
      for (int mt = 0; mt < 4; ++mt)
        af[mt] = *(const short8*)(As + (wm * 64 + mt * 16 + l16) * 72 + kk * 32 + quad * 8);
#pragma unroll
      for (int nt = 0; nt < 4; ++nt)
        bfv[nt] = *(const short8*)(Bs + (wn * 64 + nt * 16 + l16) * 72 + kk * 32 + quad * 8);
#pragma unroll
      for (int mt = 0; mt < 4; ++mt)
#pragma unroll
        for (int nt = 0; nt < 4; ++nt)
          acc[mt][nt] = __builtin_amdgcn_mfma_f32_16x16x32_bf16(af[mt], bfv[nt], acc[mt][nt], 0, 0, 0);
    }
    __syncthreads();
  }

  unsigned short* P  = QKV + (size_t)part * 16777216;   // part<3 target
  unsigned short* Vt = QKV + (size_t)3 * 16777216;
#pragma unroll
  for (int mt = 0; mt < 4; ++mt)
#pragma unroll
    for (int nt = 0; nt < 4; ++nt)
#pragma unroll
      for (int r = 0; r < 4; ++r) {
        int row = m0 + wm * 64 + mt * 16 + quad * 4 + r;
        int d   = wn * 64 + nt * 16 + l16;      // col within the 128-part
        int l = row >> 6, b = row & 63;
        int pair = b * 8 + hh;
        unsigned short val = f2b(acc[mt][nt][r]);
        if (part < 3) P[((size_t)(pair * 256 + l)) * 128 + d] = val;
        else          Vt[((size_t)(pair * 128 + d)) * 256 + l] = val;
      }
}

// =====================================================================
// K2: phi in-place.  One block per (pair,l) = bid; base = bid*128.
//   Normalizes q/k1/k2 rows: x -> (elu(x)+1)/sum.
// =====================================================================
__global__ __launch_bounds__(128) void phi_kernel(unsigned short* __restrict__ QKV) {
  int bid = blockIdx.x;                 // pair*256 + l
  int d = threadIdx.x;
  size_t base = (size_t)bid * 128 + d;
  unsigned short* Q  = QKV;
  unsigned short* K1 = QKV + 16777216;
  unsigned short* K2 = QKV + 2 * 16777216;
  float yq  = b2f(Q[base]);
  float yk1 = b2f(K1[base]);
  float yk2 = b2f(K2[base]);
  float fq  = yq  > 0.f ? yq  + 1.f : __expf(yq);
  float f1  = yk1 > 0.f ? yk1 + 1.f : __expf(yk1);
  float f2v = yk2 > 0.f ? yk2 + 1.f : __expf(yk2);
  float s0 = fq, s1 = f1, s2 = f2v;
#pragma unroll
  for (int off = 32; off; off >>= 1) {
    s0 += __shfl_down(s0, off);
    s1 += __shfl_down(s1, off);
    s2 += __shfl_down(s2, off);
  }
  __shared__ float red[3][2];
  int wv = d >> 6, lane = d & 63;
  if (lane == 0) { red[0][wv] = s0; red[1][wv] = s1; red[2][wv] = s2; }
  __syncthreads();
  float sq  = red[0][0] + red[0][1];
  float sk1 = red[1][0] + red[1][1];
  float sk2 = red[2][0] + red[2][1];
  Q[base]  = f2b(fq  / sq);
  K1[base] = f2b(f1  / sk1);
  K2[base] = f2b(f2v / sk2);
}

// =====================================================================
// K3: combined masked scores.  S[p][t][s] = mask*(pi*q.k1 + (1-pi)*q.k2)
//   per pair: M=256(t), N=256(s), K=128.  grid (2,2,512)
// =====================================================================
__global__ __launch_bounds__(256) void scores_kernel(const unsigned short* __restrict__ QKV,
                                                     const float* __restrict__ pi0,
                                                     unsigned short* __restrict__ S) {
  __shared__ alignas(16) unsigned short As[128 * 72], Bs1[128 * 72], Bs2[128 * 72];
  __shared__ float pis[128];
  int p = blockIdx.z;
  int hh = p & 7;
  int tid = threadIdx.x;
  int lane = tid & 63, wid = tid >> 6;
  int wm = wid >> 1, wn = wid & 1;
  int quad = lane >> 4, l16 = lane & 15;
  int m0 = blockIdx.y * 128, n0 = blockIdx.x * 128;
  if (tid < 128) {
    float pv = pi0[hh * 256 + m0 + tid];
    pis[tid] = fminf(fmaxf(pv, 0.f), 1.f);
  }
  const unsigned short* Qb  = QKV + (size_t)p * 32768 + (size_t)m0 * 128;
  const unsigned short* K1b = QKV + 16777216     + (size_t)p * 32768 + (size_t)n0 * 128;
  const unsigned short* K2b = QKV + 2 * 16777216 + (size_t)p * 32768 + (size_t)n0 * 128;

  floatx4 acc1[4][4], acc2[4][4];
#pragma unroll
  for (int i = 0; i < 4; ++i)
#pragma unroll
    for (int j = 0; j < 4; ++j)
#pragma unroll
      for (int r = 0; r < 4; ++r) { acc1[i][j][r] = 0.f; acc2[i][j][r] = 0.f; }

  for (int kt = 0; kt < 128; kt += 64) {
    stage_bf16(Qb + kt, 128, As, tid);
    stage_bf16(K1b + kt, 128, Bs1, tid);
    stage_bf16(K2b + kt, 128, Bs2, tid);
    __syncthreads();
#pragma unroll
    for (int kk = 0; kk < 2; ++kk) {
      short8 af[4], b1[4], b2v[4];
#pragma unroll
      for (int mt = 0; mt < 4; ++mt)
        af[mt] = *(const short8*)(As + (wm * 64 + mt * 16 + l16) * 72 + kk * 32 + quad * 8);
#pragma unroll
      for (int nt = 0; nt < 4; ++nt) {
        b1[nt]  = *(const short8*)(Bs1 + (wn * 64 + nt * 16 + l16) * 72 + kk * 32 + quad * 8);
        b2v[nt] = *(const short8*)(Bs2 + (wn * 64 + nt * 16 + l16) * 72 + kk * 32 + quad * 8);
      }
#pragma unroll
      for (int mt = 0; mt < 4; ++mt)
#pragma unroll
        for (int nt = 0; nt < 4; ++nt) {
          acc1[mt][nt] = __builtin_amdgcn_mfma_f32_16x16x32_bf16(af[mt], b1[nt],  acc1[mt][nt], 0, 0, 0);
          acc2[mt][nt] = __builtin_amdgcn_mfma_f32_16x16x32_bf16(af[mt], b2v[nt], acc2[mt][nt], 0, 0, 0);
        }
    }
    __syncthreads();
  }
#pragma unroll
  for (int mt = 0; mt < 4; ++mt)
#pragma unroll
    for (int nt = 0; nt < 4; ++nt)
#pragma unroll
      for (int r = 0; r < 4; ++r) {
        int tl = wm * 64 + mt * 16 + quad * 4 + r;
        int t = m0 + tl;
        int s = n0 + wn * 64 + nt * 16 + l16;
        float pv = pis[tl];
        float v = (s <= t) ? (pv * acc1[mt][nt][r] + (1.f - pv) * acc2[mt][nt][r]) : 0.f;
        S[(size_t)p * 65536 + (size_t)t * 256 + s] = f2b(v);
      }
}

// =====================================================================
// K4: O = SCALE * S @ V -> layer_out layout LO[(t*64+b)*1024 + h*128 + d]
//   per pair: M=256(t), N=128(d), K=256(s).  grid (1,2,512)
// =====================================================================
__global__ __launch_bounds__(256) void pv_kernel(const unsigned short* __restrict__ S,
                                                 const unsigned short* __restrict__ Vt,
                                                 unsigned short* __restrict__ LO) {
  __shared__ alignas(16) unsigned short As[128 * 72], Bs[128 * 72];
  int p = blockIdx.z;
  int b = p >> 3, hh = p & 7;
  int tid = threadIdx.x;
  int lane = tid & 63, wid = tid >> 6;
  int wm = wid >> 1, wn = wid & 1;
  int quad = lane >> 4, l16 = lane & 15;
  int m0 = blockIdx.y * 128;
  int kEnd = (blockIdx.y == 0) ? 128 : 256;   // rows t<128 only need s<128
  const unsigned short* Ab = S  + (size_t)p * 65536 + (size_t)m0 * 256;
  const unsigned short* Bb = Vt + (size_t)p * 32768;

  floatx4 acc[4][4];
#pragma unroll
  for (int i = 0; i < 4; ++i)
#pragma unroll
    for (int j = 0; j < 4; ++j)
#pragma unroll
      for (int r = 0; r < 4; ++r) acc[i][j][r] = 0.f;

  for (int kt = 0; kt < kEnd; kt += 64) {
    stage_bf16(Ab + kt, 256, As, tid);
    stage_bf16(Bb + kt, 256, Bs, tid);
    __syncthreads();
#pragma unroll
    for (int kk = 0; kk < 2; ++kk) {
      short8 af[4], bfv[4];
#pragma unroll
      for (int mt = 0; mt < 4; ++mt)
        af[mt] = *(const short8*)(As + (wm * 64 + mt * 16 + l16) * 72 + kk * 32 + quad * 8);
#pragma unroll
      for (int nt = 0; nt < 4; ++nt)
        bfv[nt] = *(const short8*)(Bs + (wn * 64 + nt * 16 + l16) * 72 + kk * 32 + quad * 8);
#pragma unroll
      for (int mt = 0; mt < 4; ++mt)
#pragma unroll
        for (int nt = 0; nt < 4; ++nt)
          acc[mt][nt] = __builtin_amdgcn_mfma_f32_16x16x32_bf16(af[mt], bfv[nt], acc[mt][nt], 0, 0, 0);
    }
    __syncthreads();
  }
#pragma unroll
  for (int mt = 0; mt < 4; ++mt)
#pragma unroll
    for (int nt = 0; nt < 4; ++nt)
#pragma unroll
      for (int r = 0; r < 4; ++r) {
        int t = m0 + wm * 64 + mt * 16 + quad * 4 + r;
        int dcol = wn * 64 + nt * 16 + l16;
        LO[((size_t)t * 64 + b) * 1024 + hh * 128 + dcol] = f2b(SCALE_ * acc[mt][nt][r]);
      }
}

// =====================================================================
// K5: X[row,m] = h[row,m] + sum_n LO[row,n]*Wo[m,n]  (X fp32 = d_out)
// =====================================================================
__global__ __launch_bounds__(256) void wo_gemm(const unsigned short* __restrict__ A,
                                               const float* __restrict__ B,
                                               const float* __restrict__ hin,
                                               float* __restrict__ X) {
  __shared__ alignas(16) unsigned short As[128 * 72], Bs[128 * 72];
  int tid = threadIdx.x;
  int lane = tid & 63, wid = tid >> 6;
  int wm = wid >> 1, wn = wid & 1;
  int quad = lane >> 4, l16 = lane & 15;
  int m0 = blockIdx.y * 128, n0 = blockIdx.x * 128;
  const unsigned short* Ab = A + (size_t)m0 * DM_;
  const float* Bb = B + (size_t)n0 * DM_;

  floatx4 acc[4][4];
#pragma unroll
  for (int i = 0; i < 4; ++i)
#pragma unroll
    for (int j = 0; j < 4; ++j)
#pragma unroll
      for (int r = 0; r < 4; ++r) acc[i][j][r] = 0.f;

  for (int kt = 0; kt < DM_; kt += 64) {
    stage_bf16(Ab + kt, DM_, As, tid);
    stage_f32(Bb + kt, DM_, Bs, tid);
    __syncthreads();
#pragma unroll
    for (int kk = 0; kk < 2; ++kk) {
      short8 af[4], bfv[4];
#pragma unroll
      for (int mt = 0; mt < 4; ++mt)
        af[mt] = *(const short8*)(As + (wm * 64 + mt * 16 + l16) * 72 + kk * 32 + quad * 8);
#pragma unroll
      for (int nt = 0; nt < 4; ++nt)
        bfv[nt] = *(const short8*)(Bs + (wn * 64 + nt * 16 + l16) * 72 + kk * 32 + quad * 8);
#pragma unroll
      for (int mt = 0; mt < 4; ++mt)
#pragma unroll
        for (int nt = 0; nt < 4; ++nt)
          acc[mt][nt] = __builtin_amdgcn_mfma_f32_16x16x32_bf16(af[mt], bfv[nt], acc[mt][nt], 0, 0, 0);
    }
    __syncthreads();
  }
#pragma unroll
  for (int mt = 0; mt < 4; ++mt)
#pragma unroll
    for (int nt = 0; nt < 4; ++nt)
#pragma unroll
      for (int r = 0; r < 4; ++r) {
        int row = m0 + wm * 64 + mt * 16 + quad * 4 + r;
        int col = n0 + wn * 64 + nt * 16 + l16;
        size_t idx = (size_t)row * DM_ + col;
        X[idx] = acc[mt][nt][r] + hin[idx];
      }
}

// =====================================================================
// K6: LayerNorm in-place on X (= d_out, fp32).  One block per row.
// =====================================================================
__global__ __launch_bounds__(256) void ln_kernel(float* __restrict__ X,
                                                 const float* __restrict__ gamma,
                                                 const float* __restrict__ beta) {
  int row = blockIdx.x;
  int tid = threadIdx.x;
  float* x = X + (size_t)row * DM_;
  float4 v = *(const float4*)(x + tid * 4);
  float s  = v.x + v.y + v.z + v.w;
  float ss = v.x * v.x + v.y * v.y + v.z * v.z + v.w * v.w;
#pragma unroll
  for (int off = 32; off; off >>= 1) {
    s  += __shfl_down(s, off);
    ss += __shfl_down(ss, off);
  }
  __shared__ float rs[4], rss[4];
  int wv = tid >> 6, lane = tid & 63;
  if (lane == 0) { rs[wv] = s; rss[wv] = ss; }
  __syncthreads();
  float St  = rs[0] + rs[1] + rs[2] + rs[3];
  float SSt = rss[0] + rss[1] + rss[2] + rss[3];
  float mu = St * (1.f / DM_);
  float var = SSt * (1.f / DM_) - mu * mu;
  float rstd = rsqrtf(var + LN_EPS_);
  float4 o;
#pragma unroll
  for (int j = 0; j < 4; ++j) {
    int c = tid * 4 + j;
    (&o.x)[j] = gamma[c] * ((&v.x)[j] - mu) * rstd + beta[c];
  }
  *(float4*)(x + tid * 4) = o;
}

// =====================================================================
extern "C" void kernel_launch(void* const* d_in, const int* in_sizes, int n_in,
                              void* d_out, int out_size, void* d_ws, size_t ws_size,
                              hipStream_t stream) {
  const float* h     = (const float*)d_in[0];
  const float* Wqkv  = (const float*)d_in[1];
  const float* Wo    = (const float*)d_in[2];
  const float* pi0   = (const float*)d_in[3];
  const float* gamma = (const float*)d_in[4];
  const float* beta  = (const float*)d_in[5];
  char* ws = (char*)d_ws;

  // ws layout (bf16 intermediates; peak 224 MB):
  //   [0,32MB)   Qraw->phi(Q)    [32,64) K1   [64,96) K2   [96,128) Vt
  //   [128,192)  S  [512][256][256]
  //   [192,224)  LO [16384][1024]
  // X (fp32 residual) lives in d_out; LN is in-place.
  unsigned short* QKV = (unsigned short*)ws;
  unsigned short* S   = (unsigned short*)(ws + 134217728);
  unsigned short* LO  = (unsigned short*)(ws + 201326592);
  float* X = (float*)d_out;

  dim3 blk(256);
  qkv_gemm<<<dim3(NQKV_ / 128, ROWS_ / 128, 1), blk, 0, stream>>>(h, Wqkv, QKV);
  phi_kernel<<<dim3(PAIRS_ * 256, 1, 1), dim3(128), 0, stream>>>(QKV);
  scores_kernel<<<dim3(2, 2, PAIRS_), blk, 0, stream>>>(QKV, pi0, S);
  pv_kernel<<<dim3(1, 2, PAIRS_), blk, 0, stream>>>(S, QKV + (size_t)3 * 16777216, LO);
  wo_gemm<<<dim3(DM_ / 128, ROWS_ / 128, 1), blk, 0, stream>>>(LO, Wo, h, X);
  ln_kernel<<<dim3(ROWS_, 1, 1), blk, 0, stream>>>(X, gamma, beta);
}

// Round 3
// 736.499 us; speedup vs baseline: 1.3530x; 1.3530x over previous
//
#include <hip/hip_runtime.h>

// ---- problem constants ----
#define H_     8
#define DM_    1024
#define NQKV_  4096
#define ROWS_  16384          // SLEN*BSZ = 256*64
#define PAIRS_ 512            // BSZ*H
#define SCALE_ 0.08838834764831845f
#define LN_EPS_ 1e-5f

typedef __attribute__((ext_vector_type(8))) short short8;   // 8 bf16 (4 VGPRs)
typedef __attribute__((ext_vector_type(4))) float floatx4;  // MFMA accumulator

__device__ __forceinline__ float b2f(unsigned short u) {
  union { unsigned int i; float f; } v; v.i = ((unsigned int)u) << 16; return v.f;
}
__device__ __forceinline__ unsigned short f2b(float f) {
  union { unsigned int i; float f; } v; v.f = f;
  unsigned int b = v.i;
  b += 0x7FFFu + ((b >> 16) & 1u);   // round-to-nearest-even
  return (unsigned short)(b >> 16);
}

// ---- async stage: 128x64 bf16 tile (row-major, ld elems) -> LDS [128][64] ----
// LDS layout is contiguous in lane order (global_load_lds constraint: dest =
// wave-uniform base + lane*16; no inner padding allowed).
__device__ __forceinline__ void stage_async(const unsigned short* __restrict__ g,
                                            int ld, unsigned short* s, int tid) {
#pragma unroll
  for (int p = 0; p < 4; ++p) {
    int idx = p * 256 + tid;
    int r = idx >> 3, c = (idx & 7) << 3;
    __builtin_amdgcn_global_load_lds(
        (const __attribute__((address_space(1))) unsigned int*)(g + (size_t)r * ld + c),
        (__attribute__((address_space(3))) unsigned int*)(s + (size_t)idx * 8),
        16, 0, 0);
  }
}

// =====================================================================
// K0: fp32 -> bf16 convert (8 elems/thread)
// =====================================================================
__global__ __launch_bounds__(256) void cvt_kernel(const float* __restrict__ src,
                                                  unsigned short* __restrict__ dst,
                                                  int n8) {
  int i = blockIdx.x * 256 + threadIdx.x;
  if (i >= n8) return;
  const float4* s4 = (const float4*)(src + (size_t)i * 8);
  float4 v0 = s4[0], v1 = s4[1];
  union { short8 v; unsigned short u[8]; } pk;
  pk.u[0] = f2b(v0.x); pk.u[1] = f2b(v0.y); pk.u[2] = f2b(v0.z); pk.u[3] = f2b(v0.w);
  pk.u[4] = f2b(v1.x); pk.u[5] = f2b(v1.y); pk.u[6] = f2b(v1.z); pk.u[7] = f2b(v1.w);
  *(short8*)(dst + (size_t)i * 8) = pk.v;
}

// =====================================================================
// K1: qkv gemm + fused phi + scatter epilogue.
//   Y[row,n] = sum_m h[row,m]*Wqkv[n,m]; each n-tile (128 cols) is one
//   complete head-part, so phi's row-sum over d=128 is block-local.
//   part<3 -> P[(pair*256+l)*128 + d] = phi value (bf16)
//   part=3 -> Vt[(pair*128+d)*256 + l] (transposed, bf16)
// =====================================================================
__global__ __launch_bounds__(256) void qkv_gemm(const unsigned short* __restrict__ A,
                                                const unsigned short* __restrict__ B,
                                                unsigned short* __restrict__ QKV) {
  __shared__ alignas(16) unsigned short As[128 * 64], Bs[128 * 64];
  int tid = threadIdx.x;
  int lane = tid & 63, wid = tid >> 6;
  int wm = wid >> 1, wn = wid & 1;
  int quad = lane >> 4, l16 = lane & 15;
  int m0 = blockIdx.y * 128, n0 = blockIdx.x * 128;
  int hh = n0 >> 9, part = (n0 >> 7) & 3;
  const unsigned short* Ab = A + (size_t)m0 * DM_;
  const unsigned short* Bb = B + (size_t)n0 * DM_;

  floatx4 acc[4][4];
#pragma unroll
  for (int i = 0; i < 4; ++i)
#pragma unroll
    for (int j = 0; j < 4; ++j)
#pragma unroll
      for (int r = 0; r < 4; ++r) acc[i][j][r] = 0.f;

  for (int kt = 0; kt < DM_; kt += 64) {
    stage_async(Ab + kt, DM_, As, tid);
    stage_async(Bb + kt, DM_, Bs, tid);
    __syncthreads();
#pragma unroll
    for (int kk = 0; kk < 2; ++kk) {
      short8 af[4], bfv[4];
#pragma unroll
      for (int mt = 0; mt < 4; ++mt)
        af[mt] = *(const short8*)(As + (wm * 64 + mt * 16 + l16) * 64 + kk * 32 + quad * 8);
#pragma unroll
      for (int nt = 0; nt < 4; ++nt)
        bfv[nt] = *(const short8*)(Bs + (wn * 64 + nt * 16 + l16) * 64 + kk * 32 + quad * 8);
#pragma unroll
      for (int mt = 0; mt < 4; ++mt)
#pragma unroll
        for (int nt = 0; nt < 4; ++nt)
          acc[mt][nt] = __builtin_amdgcn_mfma_f32_16x16x32_bf16(af[mt], bfv[nt], acc[mt][nt], 0, 0, 0);
    }
    __syncthreads();
  }

  if (part < 3) {
    unsigned short* P = QKV + (size_t)part * 16777216;
    // elu+1 in place, accumulate per-row partial sums over this wave's 64 cols
    float rsum[4][4];
#pragma unroll
    for (int mt = 0; mt < 4; ++mt)
#pragma unroll
      for (int r = 0; r < 4; ++r) rsum[mt][r] = 0.f;
#pragma unroll
    for (int mt = 0; mt < 4; ++mt)
#pragma unroll
      for (int nt = 0; nt < 4; ++nt)
#pragma unroll
        for (int r = 0; r < 4; ++r) {
          float x = acc[mt][nt][r];
          float f = x > 0.f ? x + 1.f : __expf(x);   // elu(x)+1
          acc[mt][nt][r] = f;
          rsum[mt][r] += f;
        }
    // reduce across the 16 lanes (l16) sharing each row
#pragma unroll
    for (int off = 1; off < 16; off <<= 1)
#pragma unroll
      for (int mt = 0; mt < 4; ++mt)
#pragma unroll
        for (int r = 0; r < 4; ++r)
          rsum[mt][r] += __shfl_xor(rsum[mt][r], off);
    // cross-wave (wn pair) combine via LDS (reuse As; all MFMA reads done)
    float* red = (float*)As;
    if (l16 == 0) {
#pragma unroll
      for (int mt = 0; mt < 4; ++mt)
#pragma unroll
        for (int r = 0; r < 4; ++r)
          red[wn * 128 + wm * 64 + mt * 16 + quad * 4 + r] = rsum[mt][r];
    }
    __syncthreads();
#pragma unroll
    for (int mt = 0; mt < 4; ++mt)
#pragma unroll
      for (int r = 0; r < 4; ++r) {
        int rl = wm * 64 + mt * 16 + quad * 4 + r;
        float inv = 1.f / (red[rl] + red[128 + rl]);
        int row = m0 + rl;
        int l = row >> 6, b = row & 63;
        size_t base = ((size_t)((b * 8 + hh) * 256 + l)) * 128;
#pragma unroll
        for (int nt = 0; nt < 4; ++nt) {
          int d = wn * 64 + nt * 16 + l16;
          P[base + d] = f2b(acc[mt][nt][r] * inv);
        }
      }
  } else {
    unsigned short* Vt = QKV + (size_t)3 * 16777216;
#pragma unroll
    for (int mt = 0; mt < 4; ++mt)
#pragma unroll
      for (int nt = 0; nt < 4; ++nt)
#pragma unroll
        for (int r = 0; r < 4; ++r) {
          int row = m0 + wm * 64 + mt * 16 + quad * 4 + r;
          int d = wn * 64 + nt * 16 + l16;
          int l = row >> 6, b = row & 63;
          Vt[((size_t)((b * 8 + hh) * 128 + d)) * 256 + l] = f2b(acc[mt][nt][r]);
        }
  }
}

// =====================================================================
// K3: combined masked scores.  S[p][t][s] = mask*(pi*q.k1 + (1-pi)*q.k2)
//   grid (3, 1, 512): tix 0->(m0=0,n0=0) 1->(128,0) 2->(128,128).
//   Tile (t<128, s>=128) is fully masked AND never read by pv -> skipped.
// =====================================================================
__global__ __launch_bounds__(256) void scores_kernel(const unsigned short* __restrict__ QKV,
                                                     const float* __restrict__ pi0,
                                                     unsigned short* __restrict__ S) {
  __shared__ alignas(16) unsigned short As[128 * 64], Bs1[128 * 64], Bs2[128 * 64];
  __shared__ float pis[128];
  int p = blockIdx.z;
  int hh = p & 7;
  int tid = threadIdx.x;
  int lane = tid & 63, wid = tid >> 6;
  int wm = wid >> 1, wn = wid & 1;
  int quad = lane >> 4, l16 = lane & 15;
  int tix = blockIdx.x;
  int m0 = (tix >= 1) ? 128 : 0;
  int n0 = (tix == 2) ? 128 : 0;
  if (tid < 128) {
    float pv = pi0[hh * 256 + m0 + tid];
    pis[tid] = fminf(fmaxf(pv, 0.f), 1.f);
  }
  const unsigned short* Qb  = QKV + (size_t)p * 32768 + (size_t)m0 * 128;
  const unsigned short* K1b = QKV + 16777216     + (size_t)p * 32768 + (size_t)n0 * 128;
  const unsigned short* K2b = QKV + 2 * 16777216 + (size_t)p * 32768 + (size_t)n0 * 128;

  floatx4 acc1[4][4], acc2[4][4];
#pragma unroll
  for (int i = 0; i < 4; ++i)
#pragma unroll
    for (int j = 0; j < 4; ++j)
#pragma unroll
      for (int r = 0; r < 4; ++r) { acc1[i][j][r] = 0.f; acc2[i][j][r] = 0.f; }

  for (int kt = 0; kt < 128; kt += 64) {
    stage_async(Qb + kt, 128, As, tid);
    stage_async(K1b + kt, 128, Bs1, tid);
    stage_async(K2b + kt, 128, Bs2, tid);
    __syncthreads();
#pragma unroll
    for (int kk = 0; kk < 2; ++kk) {
      short8 af[4], b1[4], b2v[4];
#pragma unroll
      for (int mt = 0; mt < 4; ++mt)
        af[mt] = *(const short8*)(As + (wm * 64 + mt * 16 + l16) * 64 + kk * 32 + quad * 8);
#pragma unroll
      for (int nt = 0; nt < 4; ++nt) {
        b1[nt]  = *(const short8*)(Bs1 + (wn * 64 + nt * 16 + l16) * 64 + kk * 32 + quad * 8);
        b2v[nt] = *(const short8*)(Bs2 + (wn * 64 + nt * 16 + l16) * 64 + kk * 32 + quad * 8);
      }
#pragma unroll
      for (int mt = 0; mt < 4; ++mt)
#pragma unroll
        for (int nt = 0; nt < 4; ++nt) {
          acc1[mt][nt] = __builtin_amdgcn_mfma_f32_16x16x32_bf16(af[mt], b1[nt],  acc1[mt][nt], 0, 0, 0);
          acc2[mt][nt] = __builtin_amdgcn_mfma_f32_16x16x32_bf16(af[mt], b2v[nt], acc2[mt][nt], 0, 0, 0);
        }
    }
    __syncthreads();
  }
#pragma unroll
  for (int mt = 0; mt < 4; ++mt)
#pragma unroll
    for (int nt = 0; nt < 4; ++nt)
#pragma unroll
      for (int r = 0; r < 4; ++r) {
        int tl = wm * 64 + mt * 16 + quad * 4 + r;
        int t = m0 + tl;
        int s = n0 + wn * 64 + nt * 16 + l16;
        float pv = pis[tl];
        float v = (s <= t) ? (pv * acc1[mt][nt][r] + (1.f - pv) * acc2[mt][nt][r]) : 0.f;
        S[(size_t)p * 65536 + (size_t)t * 256 + s] = f2b(v);
      }
}

// =====================================================================
// K4: O = SCALE * S @ V -> layer_out layout LO[(t*64+b)*1024 + h*128 + d]
//   per pair: M=256(t), N=128(d), K=256(s).  grid (1,2,512)
// =====================================================================
__global__ __launch_bounds__(256) void pv_kernel(const unsigned short* __restrict__ S,
                                                 const unsigned short* __restrict__ Vt,
                                                 unsigned short* __restrict__ LO) {
  __shared__ alignas(16) unsigned short As[128 * 64], Bs[128 * 64];
  int p = blockIdx.z;
  int b = p >> 3, hh = p & 7;
  int tid = threadIdx.x;
  int lane = tid & 63, wid = tid >> 6;
  int wm = wid >> 1, wn = wid & 1;
  int quad = lane >> 4, l16 = lane & 15;
  int m0 = blockIdx.y * 128;
  int kEnd = (blockIdx.y == 0) ? 128 : 256;   // rows t<128 only need s<128
  const unsigned short* Ab = S  + (size_t)p * 65536 + (size_t)m0 * 256;
  const unsigned short* Bb = Vt + (size_t)p * 32768;

  floatx4 acc[4][4];
#pragma unroll
  for (int i = 0; i < 4; ++i)
#pragma unroll
    for (int j = 0; j < 4; ++j)
#pragma unroll
      for (int r = 0; r < 4; ++r) acc[i][j][r] = 0.f;

  for (int kt = 0; kt < kEnd; kt += 64) {
    stage_async(Ab + kt, 256, As, tid);
    stage_async(Bb + kt, 256, Bs, tid);
    __syncthreads();
#pragma unroll
    for (int kk = 0; kk < 2; ++kk) {
      short8 af[4], bfv[4];
#pragma unroll
      for (int mt = 0; mt < 4; ++mt)
        af[mt] = *(const short8*)(As + (wm * 64 + mt * 16 + l16) * 64 + kk * 32 + quad * 8);
#pragma unroll
      for (int nt = 0; nt < 4; ++nt)
        bfv[nt] = *(const short8*)(Bs + (wn * 64 + nt * 16 + l16) * 64 + kk * 32 + quad * 8);
#pragma unroll
      for (int mt = 0; mt < 4; ++mt)
#pragma unroll
        for (int nt = 0; nt < 4; ++nt)
          acc[mt][nt] = __builtin_amdgcn_mfma_f32_16x16x32_bf16(af[mt], bfv[nt], acc[mt][nt], 0, 0, 0);
    }
    __syncthreads();
  }
#pragma unroll
  for (int mt = 0; mt < 4; ++mt)
#pragma unroll
    for (int nt = 0; nt < 4; ++nt)
#pragma unroll
      for (int r = 0; r < 4; ++r) {
        int t = m0 + wm * 64 + mt * 16 + quad * 4 + r;
        int dcol = wn * 64 + nt * 16 + l16;
        LO[((size_t)t * 64 + b) * 1024 + hh * 128 + dcol] = f2b(SCALE_ * acc[mt][nt][r]);
      }
}

// =====================================================================
// K5: X[row,m] = h[row,m] + sum_n LO[row,n]*Wo[m,n]  (X fp32 = d_out)
// =====================================================================
__global__ __launch_bounds__(256) void wo_gemm(const unsigned short* __restrict__ A,
                                               const unsigned short* __restrict__ B,
                                               const float* __restrict__ hin,
                                               float* __restrict__ X) {
  __shared__ alignas(16) unsigned short As[128 * 64], Bs[128 * 64];
  int tid = threadIdx.x;
  int lane = tid & 63, wid = tid >> 6;
  int wm = wid >> 1, wn = wid & 1;
  int quad = lane >> 4, l16 = lane & 15;
  int m0 = blockIdx.y * 128, n0 = blockIdx.x * 128;
  const unsigned short* Ab = A + (size_t)m0 * DM_;
  const unsigned short* Bb = B + (size_t)n0 * DM_;

  floatx4 acc[4][4];
#pragma unroll
  for (int i = 0; i < 4; ++i)
#pragma unroll
    for (int j = 0; j < 4; ++j)
#pragma unroll
      for (int r = 0; r < 4; ++r) acc[i][j][r] = 0.f;

  for (int kt = 0; kt < DM_; kt += 64) {
    stage_async(Ab + kt, DM_, As, tid);
    stage_async(Bb + kt, DM_, Bs, tid);
    __syncthreads();
#pragma unroll
    for (int kk = 0; kk < 2; ++kk) {
      short8 af[4], bfv[4];
#pragma unroll
      for (int mt = 0; mt < 4; ++mt)
        af[mt] = *(const short8*)(As + (wm * 64 + mt * 16 + l16) * 64 + kk * 32 + quad * 8);
#pragma unroll
      for (int nt = 0; nt < 4; ++nt)
        bfv[nt] = *(const short8*)(Bs + (wn * 64 + nt * 16 + l16) * 64 + kk * 32 + quad * 8);
#pragma unroll
      for (int mt = 0; mt < 4; ++mt)
#pragma unroll
        for (int nt = 0; nt < 4; ++nt)
          acc[mt][nt] = __builtin_amdgcn_mfma_f32_16x16x32_bf16(af[mt], bfv[nt], acc[mt][nt], 0, 0, 0);
    }
    __syncthreads();
  }
#pragma unroll
  for (int mt = 0; mt < 4; ++mt)
#pragma unroll
    for (int nt = 0; nt < 4; ++nt)
#pragma unroll
      for (int r = 0; r < 4; ++r) {
        int row = m0 + wm * 64 + mt * 16 + quad * 4 + r;
        int col = n0 + wn * 64 + nt * 16 + l16;
        size_t idx = (size_t)row * DM_ + col;
        X[idx] = acc[mt][nt][r] + hin[idx];
      }
}

// =====================================================================
// K6: LayerNorm in-place on X (= d_out, fp32).  One block per row.
// =====================================================================
__global__ __launch_bounds__(256) void ln_kernel(float* __restrict__ X,
                                                 const float* __restrict__ gamma,
                                                 const float* __restrict__ beta) {
  int row = blockIdx.x;
  int tid = threadIdx.x;
  float* x = X + (size_t)row * DM_;
  float4 v = *(const float4*)(x + tid * 4);
  float s  = v.x + v.y + v.z + v.w;
  float ss = v.x * v.x + v.y * v.y + v.z * v.z + v.w * v.w;
#pragma unroll
  for (int off = 32; off; off >>= 1) {
    s  += __shfl_down(s, off);
    ss += __shfl_down(ss, off);
  }
  __shared__ float rs[4], rss[4];
  int wv = tid >> 6, lane = tid & 63;
  if (lane == 0) { rs[wv] = s; rss[wv] = ss; }
  __syncthreads();
  float St  = rs[0] + rs[1] + rs[2] + rs[3];
  float SSt = rss[0] + rss[1] + rss[2] + rss[3];
  float mu = St * (1.f / DM_);
  float var = SSt * (1.f / DM_) - mu * mu;
  float rstd = rsqrtf(var + LN_EPS_);
  float4 o;
#pragma unroll
  for (int j = 0; j < 4; ++j) {
    int c = tid * 4 + j;
    (&o.x)[j] = gamma[c] * ((&v.x)[j] - mu) * rstd + beta[c];
  }
  *(float4*)(x + tid * 4) = o;
}

// =====================================================================
extern "C" void kernel_launch(void* const* d_in, const int* in_sizes, int n_in,
                              void* d_out, int out_size, void* d_ws, size_t ws_size,
                              hipStream_t stream) {
  const float* h     = (const float*)d_in[0];
  const float* Wqkv  = (const float*)d_in[1];
  const float* Wo    = (const float*)d_in[2];
  const float* pi0   = (const float*)d_in[3];
  const float* gamma = (const float*)d_in[4];
  const float* beta  = (const float*)d_in[5];
  char* ws = (char*)d_ws;

  // ws layout (peak 194 MB, all bf16 unless noted):
  //   [0,32M)    Q(phi)      -> after scores: reused as LO [16384][1024]
  //   [32,64)    K1          [64,96) K2        [96,128) Vt
  //   [128,192)  S [512][256][256]; first 40MB aliased pre-scores by hb+Wqkvb
  //   [128,160)  hb  (bf16 h; dead before S written)
  //   [160,168)  Wqkvb       [192,194) Wob
  // X (fp32 residual) = d_out; LN in-place.
  unsigned short* QKV   = (unsigned short*)ws;
  unsigned short* Sbuf  = (unsigned short*)(ws + 134217728ull);
  unsigned short* hb    = (unsigned short*)(ws + 134217728ull);
  unsigned short* Wqkvb = (unsigned short*)(ws + 134217728ull + 33554432ull);
  unsigned short* Wob   = (unsigned short*)(ws + 201326592ull);
  unsigned short* LO    = (unsigned short*)ws;
  float* X = (float*)d_out;

  dim3 blk(256);
  cvt_kernel<<<dim3(8192), blk, 0, stream>>>(h, hb, 2097152);
  cvt_kernel<<<dim3(2048), blk, 0, stream>>>(Wqkv, Wqkvb, 524288);
  cvt_kernel<<<dim3(512),  blk, 0, stream>>>(Wo, Wob, 131072);
  qkv_gemm<<<dim3(NQKV_ / 128, ROWS_ / 128, 1), blk, 0, stream>>>(hb, Wqkvb, QKV);
  scores_kernel<<<dim3(3, 1, PAIRS_), blk, 0, stream>>>(QKV, pi0, Sbuf);
  pv_kernel<<<dim3(1, 2, PAIRS_), blk, 0, stream>>>(Sbuf, QKV + (size_t)3 * 16777216, LO);
  wo_gemm<<<dim3(DM_ / 128, ROWS_ / 128, 1), blk, 0, stream>>>(LO, Wob, h, X);
  ln_kernel<<<dim3(ROWS_, 1, 1), blk, 0, stream>>>(X, gamma, beta);
}

// Round 4
// 653.238 us; speedup vs baseline: 1.5254x; 1.1275x over previous
//
#include <hip/hip_runtime.h>

// ---- problem constants ----
#define H_     8
#define DM_    1024
#define NQKV_  4096
#define ROWS_  16384          // SLEN*BSZ = 256*64
#define PAIRS_ 512            // BSZ*H
#define SCALE_ 0.08838834764831845f
#define LN_EPS_ 1e-5f

typedef __attribute__((ext_vector_type(8))) short short8;   // 8 bf16 (4 VGPRs)
typedef __attribute__((ext_vector_type(4))) float floatx4;  // MFMA accumulator

__device__ __forceinline__ float b2f(unsigned short u) {
  union { unsigned int i; float f; } v; v.i = ((unsigned int)u) << 16; return v.f;
}
__device__ __forceinline__ unsigned short f2b(float f) {
  union { unsigned int i; float f; } v; v.f = f;
  unsigned int b = v.i;
  b += 0x7FFFu + ((b >> 16) & 1u);   // round-to-nearest-even
  return (unsigned short)(b >> 16);
}

// ---- async stage with XOR bank swizzle ----
// LDS tile [128 rows][8 groups of 8 bf16]. LDS group j of row r holds global
// column-group (j ^ (r&7)). Dest stays lane-contiguous (global_load_lds
// constraint); source XOR keeps reads within the same 128B row segment.
__device__ __forceinline__ void stage_async(const unsigned short* __restrict__ g,
                                            int ld, unsigned short* s, int tid) {
#pragma unroll
  for (int p = 0; p < 4; ++p) {
    int idx = p * 256 + tid;
    int r = idx >> 3, j = idx & 7;
    int cg = j ^ (r & 7);
    __builtin_amdgcn_global_load_lds(
        (const __attribute__((address_space(1))) unsigned int*)(g + (size_t)r * ld + cg * 8),
        (__attribute__((address_space(3))) unsigned int*)(s + (size_t)idx * 8),
        16, 0, 0);
  }
}
// fragment read: global col-group cg of row -> LDS group cg ^ (row&7).
// consecutive rows now span all 8 bank groups: 2-way alias only (free).
__device__ __forceinline__ short8 lds_frag(const unsigned short* s, int row, int cg) {
  return *(const short8*)(s + row * 64 + ((cg ^ (row & 7)) << 3));
}

// =====================================================================
// K0: fp32 -> bf16 convert (8 elems/thread)
// =====================================================================
__global__ __launch_bounds__(256) void cvt_kernel(const float* __restrict__ src,
                                                  unsigned short* __restrict__ dst,
                                                  int n8) {
  int i = blockIdx.x * 256 + threadIdx.x;
  if (i >= n8) return;
  const float4* s4 = (const float4*)(src + (size_t)i * 8);
  float4 v0 = s4[0], v1 = s4[1];
  union { short8 v; unsigned short u[8]; } pk;
  pk.u[0] = f2b(v0.x); pk.u[1] = f2b(v0.y); pk.u[2] = f2b(v0.z); pk.u[3] = f2b(v0.w);
  pk.u[4] = f2b(v1.x); pk.u[5] = f2b(v1.y); pk.u[6] = f2b(v1.z); pk.u[7] = f2b(v1.w);
  *(short8*)(dst + (size_t)i * 8) = pk.v;
}

// =====================================================================
// K1: qkv gemm + fused phi + scatter epilogue.
// =====================================================================
__global__ __launch_bounds__(256, 4) void qkv_gemm(const unsigned short* __restrict__ A,
                                                   const unsigned short* __restrict__ B,
                                                   unsigned short* __restrict__ QKV) {
  __shared__ alignas(16) unsigned short As[128 * 64], Bs[128 * 64];
  int tid = threadIdx.x;
  int lane = tid & 63, wid = tid >> 6;
  int wm = wid >> 1, wn = wid & 1;
  int quad = lane >> 4, l16 = lane & 15;
  int m0 = blockIdx.y * 128, n0 = blockIdx.x * 128;
  int hh = n0 >> 9, part = (n0 >> 7) & 3;
  const unsigned short* Ab = A + (size_t)m0 * DM_;
  const unsigned short* Bb = B + (size_t)n0 * DM_;

  floatx4 acc[4][4];
#pragma unroll
  for (int i = 0; i < 4; ++i)
#pragma unroll
    for (int j = 0; j < 4; ++j)
#pragma unroll
      for (int r = 0; r < 4; ++r) acc[i][j][r] = 0.f;

  for (int kt = 0; kt < DM_; kt += 64) {
    stage_async(Ab + kt, DM_, As, tid);
    stage_async(Bb + kt, DM_, Bs, tid);
    __syncthreads();
#pragma unroll
    for (int kk = 0; kk < 2; ++kk) {
      short8 af[4], bfv[4];
#pragma unroll
      for (int mt = 0; mt < 4; ++mt)
        af[mt] = lds_frag(As, wm * 64 + mt * 16 + l16, kk * 4 + quad);
#pragma unroll
      for (int nt = 0; nt < 4; ++nt)
        bfv[nt] = lds_frag(Bs, wn * 64 + nt * 16 + l16, kk * 4 + quad);
#pragma unroll
      for (int mt = 0; mt < 4; ++mt)
#pragma unroll
        for (int nt = 0; nt < 4; ++nt)
          acc[mt][nt] = __builtin_amdgcn_mfma_f32_16x16x32_bf16(af[mt], bfv[nt], acc[mt][nt], 0, 0, 0);
    }
    __syncthreads();
  }

  if (part < 3) {
    unsigned short* P = QKV + (size_t)part * 16777216;
    float rsum[4][4];
#pragma unroll
    for (int mt = 0; mt < 4; ++mt)
#pragma unroll
      for (int r = 0; r < 4; ++r) rsum[mt][r] = 0.f;
#pragma unroll
    for (int mt = 0; mt < 4; ++mt)
#pragma unroll
      for (int nt = 0; nt < 4; ++nt)
#pragma unroll
        for (int r = 0; r < 4; ++r) {
          float x = acc[mt][nt][r];
          float f = x > 0.f ? x + 1.f : __expf(x);   // elu(x)+1
          acc[mt][nt][r] = f;
          rsum[mt][r] += f;
        }
#pragma unroll
    for (int off = 1; off < 16; off <<= 1)
#pragma unroll
      for (int mt = 0; mt < 4; ++mt)
#pragma unroll
        for (int r = 0; r < 4; ++r)
          rsum[mt][r] += __shfl_xor(rsum[mt][r], off);
    float* red = (float*)As;
    if (l16 == 0) {
#pragma unroll
      for (int mt = 0; mt < 4; ++mt)
#pragma unroll
        for (int r = 0; r < 4; ++r)
          red[wn * 128 + wm * 64 + mt * 16 + quad * 4 + r] = rsum[mt][r];
    }
    __syncthreads();
#pragma unroll
    for (int mt = 0; mt < 4; ++mt)
#pragma unroll
      for (int r = 0; r < 4; ++r) {
        int rl = wm * 64 + mt * 16 + quad * 4 + r;
        float inv = 1.f / (red[rl] + red[128 + rl]);
        int row = m0 + rl;
        int l = row >> 6, b = row & 63;
        size_t base = ((size_t)((b * 8 + hh) * 256 + l)) * 128;
#pragma unroll
        for (int nt = 0; nt < 4; ++nt) {
          int d = wn * 64 + nt * 16 + l16;
          P[base + d] = f2b(acc[mt][nt][r] * inv);
        }
      }
  } else {
    unsigned short* Vt = QKV + (size_t)3 * 16777216;
#pragma unroll
    for (int mt = 0; mt < 4; ++mt)
#pragma unroll
      for (int nt = 0; nt < 4; ++nt)
#pragma unroll
        for (int r = 0; r < 4; ++r) {
          int row = m0 + wm * 64 + mt * 16 + quad * 4 + r;
          int d = wn * 64 + nt * 16 + l16;
          int l = row >> 6, b = row & 63;
          Vt[((size_t)((b * 8 + hh) * 128 + d)) * 256 + l] = f2b(acc[mt][nt][r]);
        }
  }
}

// =====================================================================
// K3: combined masked scores.  grid (3, 1, 512)
// =====================================================================
__global__ __launch_bounds__(256) void scores_kernel(const unsigned short* __restrict__ QKV,
                                                     const float* __restrict__ pi0,
                                                     unsigned short* __restrict__ S) {
  __shared__ alignas(16) unsigned short As[128 * 64], Bs1[128 * 64], Bs2[128 * 64];
  __shared__ float pis[128];
  int p = blockIdx.z;
  int hh = p & 7;
  int tid = threadIdx.x;
  int lane = tid & 63, wid = tid >> 6;
  int wm = wid >> 1, wn = wid & 1;
  int quad = lane >> 4, l16 = lane & 15;
  int tix = blockIdx.x;
  int m0 = (tix >= 1) ? 128 : 0;
  int n0 = (tix == 2) ? 128 : 0;
  if (tid < 128) {
    float pv = pi0[hh * 256 + m0 + tid];
    pis[tid] = fminf(fmaxf(pv, 0.f), 1.f);
  }
  const unsigned short* Qb  = QKV + (size_t)p * 32768 + (size_t)m0 * 128;
  const unsigned short* K1b = QKV + 16777216     + (size_t)p * 32768 + (size_t)n0 * 128;
  const unsigned short* K2b = QKV + 2 * 16777216 + (size_t)p * 32768 + (size_t)n0 * 128;

  floatx4 acc1[4][4], acc2[4][4];
#pragma unroll
  for (int i = 0; i < 4; ++i)
#pragma unroll
    for (int j = 0; j < 4; ++j)
#pragma unroll
      for (int r = 0; r < 4; ++r) { acc1[i][j][r] = 0.f; acc2[i][j][r] = 0.f; }

  for (int kt = 0; kt < 128; kt += 64) {
    stage_async(Qb + kt, 128, As, tid);
    stage_async(K1b + kt, 128, Bs1, tid);
    stage_async(K2b + kt, 128, Bs2, tid);
    __syncthreads();
#pragma unroll
    for (int kk = 0; kk < 2; ++kk) {
      short8 af[4], b1[4], b2v[4];
#pragma unroll
      for (int mt = 0; mt < 4; ++mt)
        af[mt] = lds_frag(As, wm * 64 + mt * 16 + l16, kk * 4 + quad);
#pragma unroll
      for (int nt = 0; nt < 4; ++nt) {
        b1[nt]  = lds_frag(Bs1, wn * 64 + nt * 16 + l16, kk * 4 + quad);
        b2v[nt] = lds_frag(Bs2, wn * 64 + nt * 16 + l16, kk * 4 + quad);
      }
#pragma unroll
      for (int mt = 0; mt < 4; ++mt)
#pragma unroll
        for (int nt = 0; nt < 4; ++nt) {
          acc1[mt][nt] = __builtin_amdgcn_mfma_f32_16x16x32_bf16(af[mt], b1[nt],  acc1[mt][nt], 0, 0, 0);
          acc2[mt][nt] = __builtin_amdgcn_mfma_f32_16x16x32_bf16(af[mt], b2v[nt], acc2[mt][nt], 0, 0, 0);
        }
    }
    __syncthreads();
  }
#pragma unroll
  for (int mt = 0; mt < 4; ++mt)
#pragma unroll
    for (int nt = 0; nt < 4; ++nt)
#pragma unroll
      for (int r = 0; r < 4; ++r) {
        int tl = wm * 64 + mt * 16 + quad * 4 + r;
        int t = m0 + tl;
        int s = n0 + wn * 64 + nt * 16 + l16;
        float pv = pis[tl];
        float v = (s <= t) ? (pv * acc1[mt][nt][r] + (1.f - pv) * acc2[mt][nt][r]) : 0.f;
        S[(size_t)p * 65536 + (size_t)t * 256 + s] = f2b(v);
      }
}

// =====================================================================
// K4: O = SCALE * S @ V -> LO[(t*64+b)*1024 + h*128 + d].  grid (1,2,512)
// =====================================================================
__global__ __launch_bounds__(256, 4) void pv_kernel(const unsigned short* __restrict__ S,
                                                    const unsigned short* __restrict__ Vt,
                                                    unsigned short* __restrict__ LO) {
  __shared__ alignas(16) unsigned short As[128 * 64], Bs[128 * 64];
  int p = blockIdx.z;
  int b = p >> 3, hh = p & 7;
  int tid = threadIdx.x;
  int lane = tid & 63, wid = tid >> 6;
  int wm = wid >> 1, wn = wid & 1;
  int quad = lane >> 4, l16 = lane & 15;
  int m0 = blockIdx.y * 128;
  int kEnd = (blockIdx.y == 0) ? 128 : 256;   // rows t<128 only need s<128
  const unsigned short* Ab = S  + (size_t)p * 65536 + (size_t)m0 * 256;
  const unsigned short* Bb = Vt + (size_t)p * 32768;

  floatx4 acc[4][4];
#pragma unroll
  for (int i = 0; i < 4; ++i)
#pragma unroll
    for (int j = 0; j < 4; ++j)
#pragma unroll
      for (int r = 0; r < 4; ++r) acc[i][j][r] = 0.f;

  for (int kt = 0; kt < kEnd; kt += 64) {
    stage_async(Ab + kt, 256, As, tid);
    stage_async(Bb + kt, 256, Bs, tid);
    __syncthreads();
#pragma unroll
    for (int kk = 0; kk < 2; ++kk) {
      short8 af[4], bfv[4];
#pragma unroll
      for (int mt = 0; mt < 4; ++mt)
        af[mt] = lds_frag(As, wm * 64 + mt * 16 + l16, kk * 4 + quad);
#pragma unroll
      for (int nt = 0; nt < 4; ++nt)
        bfv[nt] = lds_frag(Bs, wn * 64 + nt * 16 + l16, kk * 4 + quad);
#pragma unroll
      for (int mt = 0; mt < 4; ++mt)
#pragma unroll
        for (int nt = 0; nt < 4; ++nt)
          acc[mt][nt] = __builtin_amdgcn_mfma_f32_16x16x32_bf16(af[mt], bfv[nt], acc[mt][nt], 0, 0, 0);
    }
    __syncthreads();
  }
#pragma unroll
  for (int mt = 0; mt < 4; ++mt)
#pragma unroll
    for (int nt = 0; nt < 4; ++nt)
#pragma unroll
      for (int r = 0; r < 4; ++r) {
        int t = m0 + wm * 64 + mt * 16 + quad * 4 + r;
        int dcol = wn * 64 + nt * 16 + l16;
        LO[((size_t)t * 64 + b) * 1024 + hh * 128 + dcol] = f2b(SCALE_ * acc[mt][nt][r]);
      }
}

// =====================================================================
// K5: X[row,m] = h[row,m] + sum_n LO[row,n]*Wo[m,n]  (X fp32 = d_out)
// =====================================================================
__global__ __launch_bounds__(256, 4) void wo_gemm(const unsigned short* __restrict__ A,
                                                  const unsigned short* __restrict__ B,
                                                  const float* __restrict__ hin,
                                                  float* __restrict__ X) {
  __shared__ alignas(16) unsigned short As[128 * 64], Bs[128 * 64];
  int tid = threadIdx.x;
  int lane = tid & 63, wid = tid >> 6;
  int wm = wid >> 1, wn = wid & 1;
  int quad = lane >> 4, l16 = lane & 15;
  int m0 = blockIdx.y * 128, n0 = blockIdx.x * 128;
  const unsigned short* Ab = A + (size_t)m0 * DM_;
  const unsigned short* Bb = B + (size_t)n0 * DM_;

  floatx4 acc[4][4];
#pragma unroll
  for (int i = 0; i < 4; ++i)
#pragma unroll
    for (int j = 0; j < 4; ++j)
#pragma unroll
      for (int r = 0; r < 4; ++r) acc[i][j][r] = 0.f;

  for (int kt = 0; kt < DM_; kt += 64) {
    stage_async(Ab + kt, DM_, As, tid);
    stage_async(Bb + kt, DM_, Bs, tid);
    __syncthreads();
#pragma unroll
    for (int kk = 0; kk < 2; ++kk) {
      short8 af[4], bfv[4];
#pragma unroll
      for (int mt = 0; mt < 4; ++mt)
        af[mt] = lds_frag(As, wm * 64 + mt * 16 + l16, kk * 4 + quad);
#pragma unroll
      for (int nt = 0; nt < 4; ++nt)
        bfv[nt] = lds_frag(Bs, wn * 64 + nt * 16 + l16, kk * 4 + quad);
#pragma unroll
      for (int mt = 0; mt < 4; ++mt)
#pragma unroll
        for (int nt = 0; nt < 4; ++nt)
          acc[mt][nt] = __builtin_amdgcn_mfma_f32_16x16x32_bf16(af[mt], bfv[nt], acc[mt][nt], 0, 0, 0);
    }
    __syncthreads();
  }
#pragma unroll
  for (int mt = 0; mt < 4; ++mt)
#pragma unroll
    for (int nt = 0; nt < 4; ++nt)
#pragma unroll
      for (int r = 0; r < 4; ++r) {
        int row = m0 + wm * 64 + mt * 16 + quad * 4 + r;
        int col = n0 + wn * 64 + nt * 16 + l16;
        size_t idx = (size_t)row * DM_ + col;
        X[idx] = acc[mt][nt][r] + hin[idx];
      }
}

// =====================================================================
// K6: LayerNorm in-place on X (= d_out, fp32).  One block per row.
// =====================================================================
__global__ __launch_bounds__(256) void ln_kernel(float* __restrict__ X,
                                                 const float* __restrict__ gamma,
                                                 const float* __restrict__ beta) {
  int row = blockIdx.x;
  int tid = threadIdx.x;
  float* x = X + (size_t)row * DM_;
  float4 v = *(const float4*)(x + tid * 4);
  float s  = v.x + v.y + v.z + v.w;
  float ss = v.x * v.x + v.y * v.y + v.z * v.z + v.w * v.w;
#pragma unroll
  for (int off = 32; off; off >>= 1) {
    s  += __shfl_down(s, off);
    ss += __shfl_down(ss, off);
  }
  __shared__ float rs[4], rss[4];
  int wv = tid >> 6, lane = tid & 63;
  if (lane == 0) { rs[wv] = s; rss[wv] = ss; }
  __syncthreads();
  float St  = rs[0] + rs[1] + rs[2] + rs[3];
  float SSt = rss[0] + rss[1] + rss[2] + rss[3];
  float mu = St * (1.f / DM_);
  float var = SSt * (1.f / DM_) - mu * mu;
  float rstd = rsqrtf(var + LN_EPS_);
  float4 o;
#pragma unroll
  for (int j = 0; j < 4; ++j) {
    int c = tid * 4 + j;
    (&o.x)[j] = gamma[c] * ((&v.x)[j] - mu) * rstd + beta[c];
  }
  *(float4*)(x + tid * 4) = o;
}

// =====================================================================
extern "C" void kernel_launch(void* const* d_in, const int* in_sizes, int n_in,
                              void* d_out, int out_size, void* d_ws, size_t ws_size,
                              hipStream_t stream) {
  const float* h     = (const float*)d_in[0];
  const float* Wqkv  = (const float*)d_in[1];
  const float* Wo    = (const float*)d_in[2];
  const float* pi0   = (const float*)d_in[3];
  const float* gamma = (const float*)d_in[4];
  const float* beta  = (const float*)d_in[5];
  char* ws = (char*)d_ws;

  // ws layout (peak 194 MB, all bf16 unless noted):
  //   [0,32M)    Q(phi)      -> after scores: reused as LO [16384][1024]
  //   [32,64)    K1          [64,96) K2        [96,128) Vt
  //   [128,192)  S [512][256][256]; first 40MB aliased pre-scores by hb+Wqkvb
  //   [128,160)  hb  (bf16 h; dead before S written)
  //   [160,168)  Wqkvb       [192,194) Wob
  // X (fp32 residual) = d_out; LN in-place.
  unsigned short* QKV   = (unsigned short*)ws;
  unsigned short* Sbuf  = (unsigned short*)(ws + 134217728ull);
  unsigned short* hb    = (unsigned short*)(ws + 134217728ull);
  unsigned short* Wqkvb = (unsigned short*)(ws + 134217728ull + 33554432ull);
  unsigned short* Wob   = (unsigned short*)(ws + 201326592ull);
  unsigned short* LO    = (unsigned short*)ws;
  float* X = (float*)d_out;

  dim3 blk(256);
  cvt_kernel<<<dim3(8192), blk, 0, stream>>>(h, hb, 2097152);
  cvt_kernel<<<dim3(2048), blk, 0, stream>>>(Wqkv, Wqkvb, 524288);
  cvt_kernel<<<dim3(512),  blk, 0, stream>>>(Wo, Wob, 131072);
  qkv_gemm<<<dim3(NQKV_ / 128, ROWS_ / 128, 1), blk, 0, stream>>>(hb, Wqkvb, QKV);
  scores_kernel<<<dim3(3, 1, PAIRS_), blk, 0, stream>>>(QKV, pi0, Sbuf);
  pv_kernel<<<dim3(1, 2, PAIRS_), blk, 0, stream>>>(Sbuf, QKV + (size_t)3 * 16777216, LO);
  wo_gemm<<<dim3(DM_ / 128, ROWS_ / 128, 1), blk, 0, stream>>>(LO, Wob, h, X);
  ln_kernel<<<dim3(ROWS_, 1, 1), blk, 0, stream>>>(X, gamma, beta);
}

// Round 5
// 494.303 us; speedup vs baseline: 2.0159x; 1.3215x over previous
//
#include <hip/hip_runtime.h>

// ---- problem constants ----
#define H_     8
#define DM_    1024
#define NQKV_  4096
#define ROWS_  16384          // SLEN*BSZ = 256*64
#define PAIRS_ 512            // BSZ*H
#define SCALE_ 0.08838834764831845f
#define LN_EPS_ 1e-5f

typedef __attribute__((ext_vector_type(8))) short short8;   // 8 bf16 (4 VGPRs)
typedef __attribute__((ext_vector_type(4))) float floatx4;  // MFMA accumulator

__device__ __forceinline__ float b2f(unsigned short u) {
  union { unsigned int i; float f; } v; v.i = ((unsigned int)u) << 16; return v.f;
}
__device__ __forceinline__ unsigned short f2b(float f) {
  union { unsigned int i; float f; } v; v.f = f;
  unsigned int b = v.i;
  b += 0x7FFFu + ((b >> 16) & 1u);   // round-to-nearest-even
  return (unsigned short)(b >> 16);
}

// ---- async stage with XOR bank swizzle ----
// LDS tile [128 rows][8 groups of 8 bf16]. LDS group j of row r holds global
// column-group (j ^ (r&7)). Dest stays lane-contiguous (global_load_lds
// constraint); source XOR keeps reads within the same 128B row segment.
__device__ __forceinline__ void stage_async(const unsigned short* __restrict__ g,
                                            size_t ld, unsigned short* s, int tid) {
#pragma unroll
  for (int p = 0; p < 4; ++p) {
    int idx = p * 256 + tid;
    int r = idx >> 3, j = idx & 7;
    int cg = j ^ (r & 7);
    __builtin_amdgcn_global_load_lds(
        (const __attribute__((address_space(1))) unsigned int*)(g + (size_t)r * ld + cg * 8),
        (__attribute__((address_space(3))) unsigned int*)(s + (size_t)idx * 8),
        16, 0, 0);
  }
}
// fragment read: global col-group cg of row -> LDS group cg ^ (row&7).
__device__ __forceinline__ short8 lds_frag(const unsigned short* s, int row, int cg) {
  return *(const short8*)(s + row * 64 + ((cg ^ (row & 7)) << 3));
}

// =====================================================================
// K0: fused fp32 -> bf16 convert of h, Wqkv, Wo (8 elems/thread)
//   grid covers exactly 2752512 threads (2097152 + 524288 + 131072)
// =====================================================================
__global__ __launch_bounds__(256) void cvt_all(const float* __restrict__ h,
                                               const float* __restrict__ wq,
                                               const float* __restrict__ wo,
                                               unsigned short* __restrict__ hb,
                                               unsigned short* __restrict__ wqb,
                                               unsigned short* __restrict__ wob) {
  int i = blockIdx.x * 256 + threadIdx.x;
  const float* src; unsigned short* dst; int off;
  if (i < 2097152)      { src = h;  dst = hb;  off = i; }
  else if (i < 2621440) { src = wq; dst = wqb; off = i - 2097152; }
  else                  { src = wo; dst = wob; off = i - 2621440; }
  const float4* s4 = (const float4*)(src + (size_t)off * 8);
  float4 v0 = s4[0], v1 = s4[1];
  union { short8 v; unsigned short u[8]; } pk;
  pk.u[0] = f2b(v0.x); pk.u[1] = f2b(v0.y); pk.u[2] = f2b(v0.z); pk.u[3] = f2b(v0.w);
  pk.u[4] = f2b(v1.x); pk.u[5] = f2b(v1.y); pk.u[6] = f2b(v1.z); pk.u[7] = f2b(v1.w);
  *(short8*)(dst + (size_t)off * 8) = pk.v;
}

// =====================================================================
// K1: qkv gemm + fused phi + scatter epilogue.
//   part<3 (q,k1,k2): row-major M-tiles; epilogue writes phi values, rows
//     covered contiguously in d -> L2-merged.
//   part==3 (v): b-major M-tiles (fixed b, 128 consecutive l); epilogue
//     transposes C in LDS and writes Vt[(pair*128+d)*256+l] with coalesced
//     16B stores (256B contiguous per d).
// =====================================================================
__global__ __launch_bounds__(256, 4) void qkv_gemm(const unsigned short* __restrict__ A,
                                                   const unsigned short* __restrict__ B,
                                                   unsigned short* __restrict__ QKV) {
  // union buffer: staging 2x(128x64) shorts = 16384; transpose [128][136] = 17408
  __shared__ alignas(16) unsigned short Sh[17408];
  unsigned short* As = Sh;
  unsigned short* Bs = Sh + 8192;
  int tid = threadIdx.x;
  int lane = tid & 63, wid = tid >> 6;
  int wm = wid >> 1, wn = wid & 1;
  int quad = lane >> 4, l16 = lane & 15;
  int m0 = blockIdx.y * 128, n0 = blockIdx.x * 128;
  int hh = n0 >> 9, part = (n0 >> 7) & 3;
  int bb = blockIdx.y & 63, lhalf = blockIdx.y >> 6;   // b-major mapping (part==3)

  const unsigned short* Ab;
  size_t lda;
  if (part == 3) { Ab = A + ((size_t)(lhalf * 128) * 64 + bb) * DM_; lda = (size_t)64 * DM_; }
  else           { Ab = A + (size_t)m0 * DM_;                        lda = DM_; }
  const unsigned short* Bb = B + (size_t)n0 * DM_;

  floatx4 acc[4][4];
#pragma unroll
  for (int i = 0; i < 4; ++i)
#pragma unroll
    for (int j = 0; j < 4; ++j)
#pragma unroll
      for (int r = 0; r < 4; ++r) acc[i][j][r] = 0.f;

  for (int kt = 0; kt < DM_; kt += 64) {
    stage_async(Ab + kt, lda, As, tid);
    stage_async(Bb + kt, DM_, Bs, tid);
    __syncthreads();
#pragma unroll
    for (int kk = 0; kk < 2; ++kk) {
      short8 af[4], bfv[4];
#pragma unroll
      for (int mt = 0; mt < 4; ++mt)
        af[mt] = lds_frag(As, wm * 64 + mt * 16 + l16, kk * 4 + quad);
#pragma unroll
      for (int nt = 0; nt < 4; ++nt)
        bfv[nt] = lds_frag(Bs, wn * 64 + nt * 16 + l16, kk * 4 + quad);
#pragma unroll
      for (int mt = 0; mt < 4; ++mt)
#pragma unroll
        for (int nt = 0; nt < 4; ++nt)
          acc[mt][nt] = __builtin_amdgcn_mfma_f32_16x16x32_bf16(af[mt], bfv[nt], acc[mt][nt], 0, 0, 0);
    }
    __syncthreads();
  }

  if (part < 3) {
    unsigned short* P = QKV + (size_t)part * 16777216;
    float rsum[4][4];
#pragma unroll
    for (int mt = 0; mt < 4; ++mt)
#pragma unroll
      for (int r = 0; r < 4; ++r) rsum[mt][r] = 0.f;
#pragma unroll
    for (int mt = 0; mt < 4; ++mt)
#pragma unroll
      for (int nt = 0; nt < 4; ++nt)
#pragma unroll
        for (int r = 0; r < 4; ++r) {
          float x = acc[mt][nt][r];
          float f = x > 0.f ? x + 1.f : __expf(x);   // elu(x)+1
          acc[mt][nt][r] = f;
          rsum[mt][r] += f;
        }
#pragma unroll
    for (int off = 1; off < 16; off <<= 1)
#pragma unroll
      for (int mt = 0; mt < 4; ++mt)
#pragma unroll
        for (int r = 0; r < 4; ++r)
          rsum[mt][r] += __shfl_xor(rsum[mt][r], off);
    float* red = (float*)Sh;
    if (l16 == 0) {
#pragma unroll
      for (int mt = 0; mt < 4; ++mt)
#pragma unroll
        for (int r = 0; r < 4; ++r)
          red[wn * 128 + wm * 64 + mt * 16 + quad * 4 + r] = rsum[mt][r];
    }
    __syncthreads();
#pragma unroll
    for (int mt = 0; mt < 4; ++mt)
#pragma unroll
      for (int r = 0; r < 4; ++r) {
        int rl = wm * 64 + mt * 16 + quad * 4 + r;
        float inv = 1.f / (red[rl] + red[128 + rl]);
        int row = m0 + rl;
        int l = row >> 6, b = row & 63;
        size_t base = ((size_t)((b * 8 + hh) * 256 + l)) * 128;
#pragma unroll
        for (int nt = 0; nt < 4; ++nt) {
          int d = wn * 64 + nt * 16 + l16;
          P[base + d] = f2b(acc[mt][nt][r] * inv);
        }
      }
  } else {
    // transpose via LDS: T[d][136] <- C[l][d], then coalesced Vt stores
    unsigned short* T = Sh;
#pragma unroll
    for (int mt = 0; mt < 4; ++mt)
#pragma unroll
      for (int nt = 0; nt < 4; ++nt)
#pragma unroll
        for (int r = 0; r < 4; ++r) {
          int l = wm * 64 + mt * 16 + quad * 4 + r;
          int d = wn * 64 + nt * 16 + l16;
          T[d * 136 + l] = f2b(acc[mt][nt][r]);
        }
    __syncthreads();
    unsigned short* Vt = QKV + (size_t)3 * 16777216;
    int d = tid >> 1, lb = (tid & 1) * 64;
    size_t gbase = ((size_t)((bb * 8 + hh) * 128 + d)) * 256 + lhalf * 128 + lb;
    const unsigned short* trow = T + d * 136 + lb;
#pragma unroll
    for (int j = 0; j < 8; ++j)
      *(short8*)(Vt + gbase + j * 8) = *(const short8*)(trow + j * 8);
  }
}

// =====================================================================
// K3: combined masked scores.  grid (3, 1, 512)
// =====================================================================
__global__ __launch_bounds__(256) void scores_kernel(const unsigned short* __restrict__ QKV,
                                                     const float* __restrict__ pi0,
                                                     unsigned short* __restrict__ S) {
  __shared__ alignas(16) unsigned short As[128 * 64], Bs1[128 * 64], Bs2[128 * 64];
  __shared__ float pis[128];
  int p = blockIdx.z;
  int hh = p & 7;
  int tid = threadIdx.x;
  int lane = tid & 63, wid = tid >> 6;
  int wm = wid >> 1, wn = wid & 1;
  int quad = lane >> 4, l16 = lane & 15;
  int tix = blockIdx.x;
  int m0 = (tix >= 1) ? 128 : 0;
  int n0 = (tix == 2) ? 128 : 0;
  if (tid < 128) {
    float pv = pi0[hh * 256 + m0 + tid];
    pis[tid] = fminf(fmaxf(pv, 0.f), 1.f);
  }
  const unsigned short* Qb  = QKV + (size_t)p * 32768 + (size_t)m0 * 128;
  const unsigned short* K1b = QKV + 16777216     + (size_t)p * 32768 + (size_t)n0 * 128;
  const unsigned short* K2b = QKV + 2 * 16777216 + (size_t)p * 32768 + (size_t)n0 * 128;

  floatx4 acc1[4][4], acc2[4][4];
#pragma unroll
  for (int i = 0; i < 4; ++i)
#pragma unroll
    for (int j = 0; j < 4; ++j)
#pragma unroll
      for (int r = 0; r < 4; ++r) { acc1[i][j][r] = 0.f; acc2[i][j][r] = 0.f; }

  for (int kt = 0; kt < 128; kt += 64) {
    stage_async(Qb + kt, 128, As, tid);
    stage_async(K1b + kt, 128, Bs1, tid);
    stage_async(K2b + kt, 128, Bs2, tid);
    __syncthreads();
#pragma unroll
    for (int kk = 0; kk < 2; ++kk) {
      short8 af[4], b1[4], b2v[4];
#pragma unroll
      for (int mt = 0; mt < 4; ++mt)
        af[mt] = lds_frag(As, wm * 64 + mt * 16 + l16, kk * 4 + quad);
#pragma unroll
      for (int nt = 0; nt < 4; ++nt) {
        b1[nt]  = lds_frag(Bs1, wn * 64 + nt * 16 + l16, kk * 4 + quad);
        b2v[nt] = lds_frag(Bs2, wn * 64 + nt * 16 + l16, kk * 4 + quad);
      }
#pragma unroll
      for (int mt = 0; mt < 4; ++mt)
#pragma unroll
        for (int nt = 0; nt < 4; ++nt) {
          acc1[mt][nt] = __builtin_amdgcn_mfma_f32_16x16x32_bf16(af[mt], b1[nt],  acc1[mt][nt], 0, 0, 0);
          acc2[mt][nt] = __builtin_amdgcn_mfma_f32_16x16x32_bf16(af[mt], b2v[nt], acc2[mt][nt], 0, 0, 0);
        }
    }
    __syncthreads();
  }
#pragma unroll
  for (int mt = 0; mt < 4; ++mt)
#pragma unroll
    for (int nt = 0; nt < 4; ++nt)
#pragma unroll
      for (int r = 0; r < 4; ++r) {
        int tl = wm * 64 + mt * 16 + quad * 4 + r;
        int t = m0 + tl;
        int s = n0 + wn * 64 + nt * 16 + l16;
        float pv = pis[tl];
        float v = (s <= t) ? (pv * acc1[mt][nt][r] + (1.f - pv) * acc2[mt][nt][r]) : 0.f;
        S[(size_t)p * 65536 + (size_t)t * 256 + s] = f2b(v);
      }
}

// =====================================================================
// K4: O = SCALE * S @ V -> LO[(t*64+b)*1024 + h*128 + d].  grid (1,2,512)
// =====================================================================
__global__ __launch_bounds__(256, 4) void pv_kernel(const unsigned short* __restrict__ S,
                                                    const unsigned short* __restrict__ Vt,
                                                    unsigned short* __restrict__ LO) {
  __shared__ alignas(16) unsigned short As[128 * 64], Bs[128 * 64];
  int p = blockIdx.z;
  int b = p >> 3, hh = p & 7;
  int tid = threadIdx.x;
  int lane = tid & 63, wid = tid >> 6;
  int wm = wid >> 1, wn = wid & 1;
  int quad = lane >> 4, l16 = lane & 15;
  int m0 = blockIdx.y * 128;
  int kEnd = (blockIdx.y == 0) ? 128 : 256;   // rows t<128 only need s<128
  const unsigned short* Ab = S  + (size_t)p * 65536 + (size_t)m0 * 256;
  const unsigned short* Bb = Vt + (size_t)p * 32768;

  floatx4 acc[4][4];
#pragma unroll
  for (int i = 0; i < 4; ++i)
#pragma unroll
    for (int j = 0; j < 4; ++j)
#pragma unroll
      for (int r = 0; r < 4; ++r) acc[i][j][r] = 0.f;

  for (int kt = 0; kt < kEnd; kt += 64) {
    stage_async(Ab + kt, 256, As, tid);
    stage_async(Bb + kt, 256, Bs, tid);
    __syncthreads();
#pragma unroll
    for (int kk = 0; kk < 2; ++kk) {
      short8 af[4], bfv[4];
#pragma unroll
      for (int mt = 0; mt < 4; ++mt)
        af[mt] = lds_frag(As, wm * 64 + mt * 16 + l16, kk * 4 + quad);
#pragma unroll
      for (int nt = 0; nt < 4; ++nt)
        bfv[nt] = lds_frag(Bs, wn * 64 + nt * 16 + l16, kk * 4 + quad);
#pragma unroll
      for (int mt = 0; mt < 4; ++mt)
#pragma unroll
        for (int nt = 0; nt < 4; ++nt)
          acc[mt][nt] = __builtin_amdgcn_mfma_f32_16x16x32_bf16(af[mt], bfv[nt], acc[mt][nt], 0, 0, 0);
    }
    __syncthreads();
  }
#pragma unroll
  for (int mt = 0; mt < 4; ++mt)
#pragma unroll
    for (int nt = 0; nt < 4; ++nt)
#pragma unroll
      for (int r = 0; r < 4; ++r) {
        int t = m0 + wm * 64 + mt * 16 + quad * 4 + r;
        int dcol = wn * 64 + nt * 16 + l16;
        LO[((size_t)t * 64 + b) * 1024 + hh * 128 + dcol] = f2b(SCALE_ * acc[mt][nt][r]);
      }
}

// =====================================================================
// K5: X[row,m] = h[row,m] + sum_n LO[row,n]*Wo[m,n]  (X fp32 = d_out)
// =====================================================================
__global__ __launch_bounds__(256, 4) void wo_gemm(const unsigned short* __restrict__ A,
                                                  const unsigned short* __restrict__ B,
                                                  const float* __restrict__ hin,
                                                  float* __restrict__ X) {
  __shared__ alignas(16) unsigned short As[128 * 64], Bs[128 * 64];
  int tid = threadIdx.x;
  int lane = tid & 63, wid = tid >> 6;
  int wm = wid >> 1, wn = wid & 1;
  int quad = lane >> 4, l16 = lane & 15;
  int m0 = blockIdx.y * 128, n0 = blockIdx.x * 128;
  const unsigned short* Ab = A + (size_t)m0 * DM_;
  const unsigned short* Bb = B + (size_t)n0 * DM_;

  floatx4 acc[4][4];
#pragma unroll
  for (int i = 0; i < 4; ++i)
#pragma unroll
    for (int j = 0; j < 4; ++j)
#pragma unroll
      for (int r = 0; r < 4; ++r) acc[i][j][r] = 0.f;

  for (int kt = 0; kt < DM_; kt += 64) {
    stage_async(Ab + kt, DM_, As, tid);
    stage_async(Bb + kt, DM_, Bs, tid);
    __syncthreads();
#pragma unroll
    for (int kk = 0; kk < 2; ++kk) {
      short8 af[4], bfv[4];
#pragma unroll
      for (int mt = 0; mt < 4; ++mt)
        af[mt] = lds_frag(As, wm * 64 + mt * 16 + l16, kk * 4 + quad);
#pragma unroll
      for (int nt = 0; nt < 4; ++nt)
        bfv[nt] = lds_frag(Bs, wn * 64 + nt * 16 + l16, kk * 4 + quad);
#pragma unroll
      for (int mt = 0; mt < 4; ++mt)
#pragma unroll
        for (int nt = 0; nt < 4; ++nt)
          acc[mt][nt] = __builtin_amdgcn_mfma_f32_16x16x32_bf16(af[mt], bfv[nt], acc[mt][nt], 0, 0, 0);
    }
    __syncthreads();
  }
#pragma unroll
  for (int mt = 0; mt < 4; ++mt)
#pragma unroll
    for (int nt = 0; nt < 4; ++nt)
#pragma unroll
      for (int r = 0; r < 4; ++r) {
        int row = m0 + wm * 64 + mt * 16 + quad * 4 + r;
        int col = n0 + wn * 64 + nt * 16 + l16;
        size_t idx = (size_t)row * DM_ + col;
        X[idx] = acc[mt][nt][r] + hin[idx];
      }
}

// =====================================================================
// K6: LayerNorm in-place on X (= d_out, fp32).  One block per row.
// =====================================================================
__global__ __launch_bounds__(256) void ln_kernel(float* __restrict__ X,
                                                 const float* __restrict__ gamma,
                                                 const float* __restrict__ beta) {
  int row = blockIdx.x;
  int tid = threadIdx.x;
  float* x = X + (size_t)row * DM_;
  float4 v = *(const float4*)(x + tid * 4);
  float s  = v.x + v.y + v.z + v.w;
  float ss = v.x * v.x + v.y * v.y + v.z * v.z + v.w * v.w;
#pragma unroll
  for (int off = 32; off; off >>= 1) {
    s  += __shfl_down(s, off);
    ss += __shfl_down(ss, off);
  }
  __shared__ float rs[4], rss[4];
  int wv = tid >> 6, lane = tid & 63;
  if (lane == 0) { rs[wv] = s; rss[wv] = ss; }
  __syncthreads();
  float St  = rs[0] + rs[1] + rs[2] + rs[3];
  float SSt = rss[0] + rss[1] + rss[2] + rss[3];
  float mu = St * (1.f / DM_);
  float var = SSt * (1.f / DM_) - mu * mu;
  float rstd = rsqrtf(var + LN_EPS_);
  float4 o;
#pragma unroll
  for (int j = 0; j < 4; ++j) {
    int c = tid * 4 + j;
    (&o.x)[j] = gamma[c] * ((&v.x)[j] - mu) * rstd + beta[c];
  }
  *(float4*)(x + tid * 4) = o;
}

// =====================================================================
extern "C" void kernel_launch(void* const* d_in, const int* in_sizes, int n_in,
                              void* d_out, int out_size, void* d_ws, size_t ws_size,
                              hipStream_t stream) {
  const float* h     = (const float*)d_in[0];
  const float* Wqkv  = (const float*)d_in[1];
  const float* Wo    = (const float*)d_in[2];
  const float* pi0   = (const float*)d_in[3];
  const float* gamma = (const float*)d_in[4];
  const float* beta  = (const float*)d_in[5];
  char* ws = (char*)d_ws;

  // ws layout (peak 194 MB, all bf16 unless noted):
  //   [0,32M)    Q(phi)      -> after scores: reused as LO [16384][1024]
  //   [32,64)    K1          [64,96) K2        [96,128) Vt
  //   [128,192)  S [512][256][256]; first 40MB aliased pre-scores by hb+Wqkvb
  //   [128,160)  hb  (bf16 h; dead before S written)
  //   [160,168)  Wqkvb       [192,194) Wob
  // X (fp32 residual) = d_out; LN in-place.
  unsigned short* QKV   = (unsigned short*)ws;
  unsigned short* Sbuf  = (unsigned short*)(ws + 134217728ull);
  unsigned short* hb    = (unsigned short*)(ws + 134217728ull);
  unsigned short* Wqkvb = (unsigned short*)(ws + 134217728ull + 33554432ull);
  unsigned short* Wob   = (unsigned short*)(ws + 201326592ull);
  unsigned short* LO    = (unsigned short*)ws;
  float* X = (float*)d_out;

  dim3 blk(256);
  cvt_all<<<dim3(10752), blk, 0, stream>>>(h, Wqkv, Wo, hb, Wqkvb, Wob);
  qkv_gemm<<<dim3(NQKV_ / 128, ROWS_ / 128, 1), blk, 0, stream>>>(hb, Wqkvb, QKV);
  scores_kernel<<<dim3(3, 1, PAIRS_), blk, 0, stream>>>(QKV, pi0, Sbuf);
  pv_kernel<<<dim3(1, 2, PAIRS_), blk, 0, stream>>>(Sbuf, QKV + (size_t)3 * 16777216, LO);
  wo_gemm<<<dim3(DM_ / 128, ROWS_ / 128, 1), blk, 0, stream>>>(LO, Wob, h, X);
  ln_kernel<<<dim3(ROWS_, 1, 1), blk, 0, stream>>>(X, gamma, beta);
}